// Round 27
// baseline (250.078 us; speedup 1.0000x reference)
//
#include <hip/hip_runtime.h>

#define B_    32
#define C_    192
#define N_    784
#define NP_   1024        // sqp row stride (pad never read)
#define K_    9
#define COUT_ 384
#define NPTS_ (B_ * N_)   // 25088
#define NTILES_ 224       // 32 b * 7 ntiles

typedef __attribute__((ext_vector_type(8))) short short8;   // 8 bf16 = 4 VGPR
typedef __attribute__((ext_vector_type(4))) float f32x4;    // MFMA acc

// ordered-uint transform: monotone map float -> uint
__device__ __forceinline__ unsigned int ford(float f) {
  unsigned int u = __float_as_uint(f);
  return u ^ ((u & 0x80000000u) ? 0xFFFFFFFFu : 0x80000000u);
}
// fp32 -> bf16 (RNE)
__device__ __forceinline__ unsigned short f2bf(float f) {
  unsigned int u = __float_as_uint(f);
  u += 0x7FFFu + ((u >> 16) & 1u);
  return (unsigned short)(u >> 16);
}
__device__ __forceinline__ float bf2f(unsigned short h) {
  return __uint_as_float(((unsigned int)h) << 16);
}

// ---------------------------------------------------------------------------
// K1: norm + frag pack + coalesced xT via LDS transpose (proven R23).
// ---------------------------------------------------------------------------
__global__ __launch_bounds__(256) void norm_kernel(
    const float* __restrict__ x, short8* __restrict__ fragH,
    short8* __restrict__ fragL, float* __restrict__ sqp,
    float* __restrict__ xT) {
  int t = threadIdx.x;
  int pl = t & 63, cg = t >> 6;
  int p = blockIdx.x * 64 + pl;
  int b = p / N_, n = p % N_;
  const float* xb = x + (size_t)b * C_ * N_ + n;

  __shared__ float Tl[64][193];   // 49.4 KB
  __shared__ float red[4][64];
  __shared__ float nrmS[64];

  float part = 0.f;
  #pragma unroll
  for (int j = 0; j < 48; j++) {
    float v = xb[(size_t)(cg * 48 + j) * N_];
    Tl[pl][cg * 48 + j] = v;
    part = __fmaf_rn(v, v, part);
  }
  red[cg][pl] = part;
  __syncthreads();
  if (t < 64) {
    float ssq = __fadd_rn(__fadd_rn(red[0][t], red[1][t]),
                          __fadd_rn(red[2][t], red[3][t]));
    nrmS[t] = fmaxf(__fsqrt_rn(ssq), 1e-12f);
  }
  __syncthreads();

  {
    size_t base = (size_t)blockIdx.x * 64 * C_;
    for (int idx = t; idx < 64 * C_; idx += 256)
      xT[base + idx] = Tl[idx / C_][idx % C_];
  }

  float nrm = nrmS[pl];
  int g = n >> 4, li = n & 15;
  float p2 = 0.f;
  #pragma unroll
  for (int s = 0; s < 6; s++) {
    int kslot = cg * 6 + s;          // 0..23
    int ks = kslot >> 2, kq = kslot & 3;
    union { short8 v; unsigned short u[8]; } ph, plo;
    #pragma unroll
    for (int j = 0; j < 8; j++) {
      float a = __fdiv_rn(Tl[pl][kslot * 8 + j], nrm);
      unsigned short h = f2bf(a);
      ph.u[j]  = h;
      plo.u[j] = f2bf(__fsub_rn(a, bf2f(h)));
      p2 = __fmaf_rn(a, a, p2);
    }
    size_t idx = (((size_t)b * 6 + ks) * 64 + g) * 64 + (kq * 16 + li);
    fragH[idx] = ph.v;
    fragL[idx] = plo.v;
  }
  red[cg][pl] = p2;
  __syncthreads();
  if (t < 64) {
    float sq = __fadd_rn(__fadd_rn(red[0][t], red[1][t]),
                         __fadd_rn(red[2][t], red[3][t]));
    int pp = blockIdx.x * 64 + t;
    sqp[(size_t)(pp / N_) * NP_ + (pp % N_)] = sq;
  }
}

// ---------------------------------------------------------------------------
// K2: MFMA KNN — REGISTER-RESIDENT keys (kreg[4][13], all static-indexed),
//  segmented 16-lane butterfly per-wave top-9, 4.6 KB LDS partials + merge.
//  LDS 53KB -> 4.6KB => occupancy VGPR-bound (~4 blocks/CU).
//  Distance chains bit-identical to R26; selection semantics identical
//  (same keys, same lex (value, lowest-col) order, slice-top9 U merge exact).
// ---------------------------------------------------------------------------
__global__ __launch_bounds__(256, 4) void knn_kernel(
    const short8* __restrict__ fragH, const short8* __restrict__ fragL,
    const float* __restrict__ sqp, int* __restrict__ nn9) {
  int wg = blockIdx.x;
  int r = wg & 7, j = wg >> 3;
  int b  = r + 8 * (j / 49);
  int qt = j % 49;
  int q0 = qt * 16;
  int t = threadIdx.x, lane = t & 63, w = t >> 6;

  __shared__ unsigned long long partialS[4][16][K_];  // 4.6 KB

  const float* sqb = sqp + (size_t)b * NP_;
  const short8* fH = fragH + (size_t)b * 6 * 64 * 64;
  const short8* fL = fragL + (size_t)b * 6 * 64 * 64;

  int colL = lane & 15, rq = lane >> 4;

  float qsv[4];
  #pragma unroll
  for (int rr = 0; rr < 4; rr++) qsv[rr] = sqb[q0 + rq * 4 + rr];

  short8 aH[6], aL[6];
  #pragma unroll
  for (int ks = 0; ks < 6; ks++) {
    aH[ks] = fH[((size_t)ks * 64 + qt) * 64 + lane];
    aL[ks] = fL[((size_t)ks * 64 + qt) * 64 + lane];
  }

  const int wstart = (w == 0) ? 0 : (w == 1) ? 13 : (w == 2) ? 26 : 39;
  const int wend   = (w == 3) ? 49 : (wstart + 13);

  unsigned int kreg[4][13];
  #pragma unroll
  for (int rr = 0; rr < 4; rr++)
    #pragma unroll
    for (int it = 0; it < 13; it++) kreg[rr][it] = 0xFFFFFFFFu;

  // ---- dot phase: 6 static pair-slots + 1 single tail slot ----
  #pragma unroll
  for (int slot = 0; slot < 12; slot += 2) {
    int g0 = wstart + slot, g1 = wstart + slot + 1;
    bool v0 = g0 < wend, v1 = g1 < wend;
    int g0c = v0 ? g0 : 48, g1c = v1 ? g1 : 48;
    short8 B0h[6], B0l[6], B1h[6], B1l[6];
    #pragma unroll
    for (int ks = 0; ks < 6; ks++) {
      B0h[ks] = fH[((size_t)ks * 64 + g0c) * 64 + lane];
      B0l[ks] = fL[((size_t)ks * 64 + g0c) * 64 + lane];
      B1h[ks] = fH[((size_t)ks * 64 + g1c) * 64 + lane];
      B1l[ks] = fL[((size_t)ks * 64 + g1c) * 64 + lane];
    }
    float cs0 = sqb[g0c * 16 + colL];
    float cs1 = sqb[g1c * 16 + colL];
    f32x4 a00 = {0.f, 0.f, 0.f, 0.f}, a01 = a00, a02 = a00;
    f32x4 a10 = a00, a11 = a00, a12 = a00;
    #pragma unroll
    for (int ks = 0; ks < 6; ks++) {
      a00 = __builtin_amdgcn_mfma_f32_16x16x32_bf16(aH[ks], B0h[ks], a00, 0, 0, 0);
      a01 = __builtin_amdgcn_mfma_f32_16x16x32_bf16(aH[ks], B0l[ks], a01, 0, 0, 0);
      a02 = __builtin_amdgcn_mfma_f32_16x16x32_bf16(aL[ks], B0h[ks], a02, 0, 0, 0);
      a10 = __builtin_amdgcn_mfma_f32_16x16x32_bf16(aH[ks], B1h[ks], a10, 0, 0, 0);
      a11 = __builtin_amdgcn_mfma_f32_16x16x32_bf16(aH[ks], B1l[ks], a11, 0, 0, 0);
      a12 = __builtin_amdgcn_mfma_f32_16x16x32_bf16(aL[ks], B1h[ks], a12, 0, 0, 0);
    }
    #pragma unroll
    for (int rr = 0; rr < 4; rr++) {
      float qs = qsv[rr];
      float g0v = __fadd_rn(__fadd_rn(a00[rr], a01[rr]), a02[rr]);
      float g1v = __fadd_rn(__fadd_rn(a10[rr], a11[rr]), a12[rr]);
      float d0 = __fadd_rn(__fsub_rn(qs, __fmul_rn(2.0f, g0v)), cs0);
      float d1 = __fadd_rn(__fsub_rn(qs, __fmul_rn(2.0f, g1v)), cs1);
      if (v0) kreg[rr][slot]     = ford(d0);
      if (v1) kreg[rr][slot + 1] = ford(d1);
    }
  }
  {
    int g0 = wstart + 12;
    bool v0 = g0 < wend;
    int g0c = v0 ? g0 : 48;
    short8 B0h[6], B0l[6];
    #pragma unroll
    for (int ks = 0; ks < 6; ks++) {
      B0h[ks] = fH[((size_t)ks * 64 + g0c) * 64 + lane];
      B0l[ks] = fL[((size_t)ks * 64 + g0c) * 64 + lane];
    }
    float cs0 = sqb[g0c * 16 + colL];
    f32x4 a00 = {0.f, 0.f, 0.f, 0.f}, a01 = a00, a02 = a00;
    #pragma unroll
    for (int ks = 0; ks < 6; ks++) {
      a00 = __builtin_amdgcn_mfma_f32_16x16x32_bf16(aH[ks], B0h[ks], a00, 0, 0, 0);
      a01 = __builtin_amdgcn_mfma_f32_16x16x32_bf16(aH[ks], B0l[ks], a01, 0, 0, 0);
      a02 = __builtin_amdgcn_mfma_f32_16x16x32_bf16(aL[ks], B0h[ks], a02, 0, 0, 0);
    }
    #pragma unroll
    for (int rr = 0; rr < 4; rr++) {
      float qs = qsv[rr];
      float g0v = __fadd_rn(__fadd_rn(a00[rr], a01[rr]), a02[rr]);
      float d0 = __fadd_rn(__fsub_rn(qs, __fmul_rn(2.0f, g0v)), cs0);
      if (v0) kreg[rr][12] = ford(d0);
    }
  }

  // ---- per-wave slice top-9 (segmented butterfly, registers only) ----
  #pragma unroll
  for (int rr = 0; rr < 4; rr++) {
    int row = rq * 4 + rr;
    unsigned int bv = 0xFFFFFFFFu; int bit = 0;
    #pragma unroll
    for (int it = 0; it < 13; it++)
      if (kreg[rr][it] < bv) { bv = kreg[rr][it]; bit = it; }
    for (int kk = 0; kk < K_; kk++) {
      unsigned long long mk =
          ((unsigned long long)bv << 10) |
          (unsigned int)((wstart + bit) * 16 + colL);
      #pragma unroll
      for (int off = 1; off < 16; off <<= 1) {     // segmented (16-lane) min
        unsigned long long v2 = __shfl_xor(mk, off);
        mk = v2 < mk ? v2 : mk;
      }
      if (colL == 0) partialS[w][row][kk] = mk;
      int col = (int)(mk & 1023u);
      if ((col & 15) == colL) {                    // owner lane knockout
        int slot = (col >> 4) - wstart;
        #pragma unroll
        for (int it = 0; it < 13; it++)
          if (it == slot) kreg[rr][it] = 0xFFFFFFFFu;
      }
      bv = 0xFFFFFFFFu; bit = 0;
      #pragma unroll
      for (int it = 0; it < 13; it++)
        if (kreg[rr][it] < bv) { bv = kreg[rr][it]; bit = it; }
    }
  }
  __syncthreads();

  // ---- merge: wave w merges rows w*4..w*4+3 from 4x9 partials ----
  for (int s = 0; s < 4; s++) {
    int row = w * 4 + s;
    unsigned long long v = (lane < 36)
        ? partialS[lane / 9][row][lane % 9] : ~0ull;
    int* o = nn9 + ((size_t)b * N_ + q0 + row) * K_;
    for (int kk = 0; kk < K_; kk++) {
      unsigned long long mk = v;
      #pragma unroll
      for (int off = 1; off < 64; off <<= 1) {
        unsigned long long v2 = __shfl_xor(mk, off);
        mk = v2 < mk ? v2 : mk;
      }
      if (lane == 0) o[kk] = (int)(mk & 1023u);
      if (v == mk) v = ~0ull;   // keys unique (distinct cols)
    }
  }
}

// ---------------------------------------------------------------------------
// K3: FUSED gather + max-rel + grouped conv — merged halves, bf16 Wl (R24).
// ---------------------------------------------------------------------------
__global__ __launch_bounds__(256) void fconv_kernel(
    const float* __restrict__ xT, const int* __restrict__ nn9,
    const float* __restrict__ w, const float* __restrict__ bias,
    unsigned short* __restrict__ outpre, float* __restrict__ psum,
    float* __restrict__ pss) {
  int nt = blockIdx.x;
  int g  = blockIdx.y;
  int b  = blockIdx.z;
  int n0 = nt * 112;
  int t = threadIdx.x;

  __shared__ unsigned short Wl[96][98];   // 18.8 KB bf16
  __shared__ float Hl[96][112];           // 43.0 KB
  __shared__ unsigned short Il[112][K_];  // 2.0 KB

  const int* isrc = nn9 + ((size_t)b * N_ + n0) * K_;
  for (int i = t; i < 112 * K_; i += 256)
    Il[i / K_][i % K_] = (unsigned short)isrc[i];
  const float* wsrc = w + (size_t)(g * 96) * 96;
  for (int i = t; i < 96 * 96; i += 256)
    Wl[i / 96][i % 96] = f2bf(wsrc[i]);
  __syncthreads();

  if (t < 224) {
    int nl = t >> 1, half = t & 1;
    const float* xrow = xT + ((size_t)b * N_ + n0 + nl) * C_ + g * 48 + half * 24;
    float xv[24], mx[24];
    #pragma unroll
    for (int j = 0; j < 24; j += 4) {
      float4 v = *(const float4*)(xrow + j);
      xv[j] = v.x; xv[j + 1] = v.y; xv[j + 2] = v.z; xv[j + 3] = v.w;
      mx[j] = -1e30f; mx[j + 1] = -1e30f; mx[j + 2] = -1e30f; mx[j + 3] = -1e30f;
    }
    #pragma unroll
    for (int k = 0; k < K_; k++) {
      int idx = Il[nl][k];
      const float* nrow = xT + ((size_t)b * N_ + idx) * C_ + g * 48 + half * 24;
      #pragma unroll
      for (int j = 0; j < 24; j += 4) {
        float4 v = *(const float4*)(nrow + j);
        mx[j]     = fmaxf(mx[j], v.x);
        mx[j + 1] = fmaxf(mx[j + 1], v.y);
        mx[j + 2] = fmaxf(mx[j + 2], v.z);
        mx[j + 3] = fmaxf(mx[j + 3], v.w);
      }
    }
    #pragma unroll
    for (int j = 0; j < 24; j++) {
      int cl = half * 24 + j;
      Hl[2 * cl][nl]     = xv[j];
      Hl[2 * cl + 1][nl] = mx[j] - xv[j];
    }
  }
  __syncthreads();

  int tx = t & 15, ty = t >> 4;
  int tidx = b * 7 + nt;

  float o[6][7];
  #pragma unroll
  for (int i = 0; i < 6; i++)
    #pragma unroll
    for (int j = 0; j < 7; j++) o[i][j] = 0.f;

  for (int k = 0; k < 96; k++) {
    float wv[6];
    #pragma unroll
    for (int i = 0; i < 6; i++) wv[i] = bf2f(Wl[ty * 6 + i][k]);
    #pragma unroll
    for (int j = 0; j < 7; j++) {
      float hv = Hl[k][tx * 7 + j];
      #pragma unroll
      for (int i = 0; i < 6; i++) o[i][j] = __fmaf_rn(wv[i], hv, o[i][j]);
    }
  }

  #pragma unroll
  for (int i = 0; i < 6; i++) {
    int co = g * 96 + ty * 6 + i;
    float bv = bias[co];
    float s = 0.f, s2 = 0.f;
    unsigned short* orow =
        outpre + ((size_t)b * COUT_ + co) * N_ + n0 + tx * 7;
    #pragma unroll
    for (int j = 0; j < 7; j++) {
      float v = o[i][j] + bv;
      orow[j] = f2bf(v);
      s += v; s2 += v * v;
    }
    #pragma unroll
    for (int off = 1; off < 16; off <<= 1) {
      s  += __shfl_xor(s, off);
      s2 += __shfl_xor(s2, off);
    }
    if (tx == 0) {
      psum[co * NTILES_ + tidx] = s;
      pss [co * NTILES_ + tidx] = s2;
    }
  }
}

// ---------------------------------------------------------------------------
// K4: finalize BN stats -> per-channel affine a, b
// ---------------------------------------------------------------------------
__global__ __launch_bounds__(64) void stats_kernel(
    const float* __restrict__ psum, const float* __restrict__ pss,
    const float* __restrict__ gamma, const float* __restrict__ beta,
    float* __restrict__ af, float* __restrict__ bf) {
  int co = blockIdx.x;
  int l = threadIdx.x;
  double s = 0.0, s2 = 0.0;
  for (int i = l; i < NTILES_; i += 64) {
    s  += (double)psum[co * NTILES_ + i];
    s2 += (double)pss [co * NTILES_ + i];
  }
  #pragma unroll
  for (int o = 32; o > 0; o >>= 1) { s += __shfl_xor(s, o); s2 += __shfl_xor(s2, o); }
  if (l == 0) {
    const double cnt = (double)NPTS_;
    double mean = s / cnt;
    double var  = s2 / cnt - mean * mean;
    double rstd = 1.0 / sqrt(var + 1e-5);
    double a = (double)gamma[co] * rstd;
    af[co] = (float)a;
    bf[co] = (float)((double)beta[co] - mean * a);
  }
}

// ---------------------------------------------------------------------------
// K5: BN affine + exact GELU + fp32 store (8 elems/thread, bf16 input)
// ---------------------------------------------------------------------------
__global__ __launch_bounds__(256) void act_kernel(
    const unsigned short* __restrict__ outpre, const float* __restrict__ af,
    const float* __restrict__ bf, float* __restrict__ out) {
  size_t i = ((size_t)blockIdx.x * 256 + threadIdx.x) * 8;
  int co = (int)((i / N_) % COUT_);     // N_ % 8 == 0 -> co uniform
  float a = af[co], c = bf[co];
  union { uint4 u4; unsigned short us[8]; } pk;
  pk.u4 = *reinterpret_cast<const uint4*>(outpre + i);
  const float is2 = 0.70710678118654752f;
  float r[8];
  #pragma unroll
  for (int j = 0; j < 8; j++) {
    float y = __fmaf_rn(a, bf2f(pk.us[j]), c);
    r[j] = 0.5f * y * (1.0f + erff(y * is2));
  }
  float4 r0 = {r[0], r[1], r[2], r[3]};
  float4 r1 = {r[4], r[5], r[6], r[7]};
  *reinterpret_cast<float4*>(out + i) = r0;
  *reinterpret_cast<float4*>(out + i + 4) = r1;
}

// ---------------------------------------------------------------------------
extern "C" void kernel_launch(void* const* d_in, const int* in_sizes, int n_in,
                              void* d_out, int out_size, void* d_ws, size_t ws_size,
                              hipStream_t stream) {
  const float* x      = (const float*)d_in[0];
  const float* conv_w = (const float*)d_in[1];
  const float* conv_b = (const float*)d_in[2];
  const float* gamma  = (const float*)d_in[3];
  const float* beta   = (const float*)d_in[4];
  float* out = (float*)d_out;

  float* buf0 = (float*)d_ws;
  short8* fragH = (short8*)buf0;                         // [0, 3145728)
  short8* fragL = (short8*)(buf0 + 3145728);             // [3145728, 6291456)
  unsigned short* outpre = (unsigned short*)buf0;        // overlay (frags dead)
  float*  sqp   = buf0 + 9633792;                        // 32768
  int*    nn9   = (int*)(buf0 + 9666560);                // 225792
  float*  xT    = buf0 + 9892352;                        // 4816896
  float*  psum  = buf0 + 14709248;                       // 86016
  float*  pss   = psum + COUT_ * NTILES_;                // 86016
  float*  af    = pss + COUT_ * NTILES_;
  float*  bfv   = af + COUT_;

  hipLaunchKernelGGL(norm_kernel, dim3(NPTS_ / 64), dim3(256), 0, stream,
                     x, fragH, fragL, sqp, xT);
  hipLaunchKernelGGL(knn_kernel, dim3(49 * B_), dim3(256), 0, stream,
                     fragH, fragL, sqp, nn9);
  hipLaunchKernelGGL(fconv_kernel, dim3(7, 4, B_), dim3(256), 0, stream,
                     xT, nn9, conv_w, conv_b, outpre, psum, pss);
  hipLaunchKernelGGL(stats_kernel, dim3(COUT_), dim3(64), 0, stream,
                     psum, pss, gamma, beta, af, bfv);
  hipLaunchKernelGGL(act_kernel, dim3((B_ * COUT_ * N_) / (256 * 8)), dim3(256), 0, stream,
                     outpre, af, bfv, out);
}

// Round 28
// 188.740 us; speedup vs baseline: 1.3250x; 1.3250x over previous
//
#include <hip/hip_runtime.h>

#define B_    32
#define C_    192
#define N_    784
#define NP_   1024        // sqp row stride (pad never read)
#define K_    9
#define COUT_ 384
#define NPTS_ (B_ * N_)   // 25088
#define NTILES_ 224       // 32 b * 7 ntiles
#define DKW_  836         // dkS row stride (>= 13*64=832)

typedef __attribute__((ext_vector_type(8))) short short8;   // 8 bf16 = 4 VGPR
typedef __attribute__((ext_vector_type(4))) float f32x4;    // MFMA acc

// ordered-uint transform: monotone map float -> uint
__device__ __forceinline__ unsigned int ford(float f) {
  unsigned int u = __float_as_uint(f);
  return u ^ ((u & 0x80000000u) ? 0xFFFFFFFFu : 0x80000000u);
}
// fp32 -> bf16 (RNE)
__device__ __forceinline__ unsigned short f2bf(float f) {
  unsigned int u = __float_as_uint(f);
  u += 0x7FFFu + ((u >> 16) & 1u);
  return (unsigned short)(u >> 16);
}
__device__ __forceinline__ float bf2f(unsigned short h) {
  return __uint_as_float(((unsigned int)h) << 16);
}

// ---------------------------------------------------------------------------
// K1: norm + frag pack + coalesced xT via LDS transpose (proven R23).
// ---------------------------------------------------------------------------
__global__ __launch_bounds__(256) void norm_kernel(
    const float* __restrict__ x, short8* __restrict__ fragH,
    short8* __restrict__ fragL, float* __restrict__ sqp,
    float* __restrict__ xT) {
  int t = threadIdx.x;
  int pl = t & 63, cg = t >> 6;
  int p = blockIdx.x * 64 + pl;
  int b = p / N_, n = p % N_;
  const float* xb = x + (size_t)b * C_ * N_ + n;

  __shared__ float Tl[64][193];   // 49.4 KB
  __shared__ float red[4][64];
  __shared__ float nrmS[64];

  float part = 0.f;
  #pragma unroll
  for (int j = 0; j < 48; j++) {
    float v = xb[(size_t)(cg * 48 + j) * N_];
    Tl[pl][cg * 48 + j] = v;
    part = __fmaf_rn(v, v, part);
  }
  red[cg][pl] = part;
  __syncthreads();
  if (t < 64) {
    float ssq = __fadd_rn(__fadd_rn(red[0][t], red[1][t]),
                          __fadd_rn(red[2][t], red[3][t]));
    nrmS[t] = fmaxf(__fsqrt_rn(ssq), 1e-12f);
  }
  __syncthreads();

  {
    size_t base = (size_t)blockIdx.x * 64 * C_;
    for (int idx = t; idx < 64 * C_; idx += 256)
      xT[base + idx] = Tl[idx / C_][idx % C_];
  }

  float nrm = nrmS[pl];
  int g = n >> 4, li = n & 15;
  float p2 = 0.f;
  #pragma unroll
  for (int s = 0; s < 6; s++) {
    int kslot = cg * 6 + s;          // 0..23
    int ks = kslot >> 2, kq = kslot & 3;
    union { short8 v; unsigned short u[8]; } ph, plo;
    #pragma unroll
    for (int j = 0; j < 8; j++) {
      float a = __fdiv_rn(Tl[pl][kslot * 8 + j], nrm);
      unsigned short h = f2bf(a);
      ph.u[j]  = h;
      plo.u[j] = f2bf(__fsub_rn(a, bf2f(h)));
      p2 = __fmaf_rn(a, a, p2);
    }
    size_t idx = (((size_t)b * 6 + ks) * 64 + g) * 64 + (kq * 16 + li);
    fragH[idx] = ph.v;
    fragL[idx] = plo.v;
  }
  red[cg][pl] = p2;
  __syncthreads();
  if (t < 64) {
    float sq = __fadd_rn(__fadd_rn(red[0][t], red[1][t]),
                         __fadd_rn(red[2][t], red[3][t]));
    int pp = blockIdx.x * 64 + t;
    sqp[(size_t)(pp / N_) * NP_ + (pp % N_)] = sq;
  }
}

// ---------------------------------------------------------------------------
// K2: MFMA KNN — proven R25 version (103 us): dkS[16][836] LDS keys,
//  13-strip scan + owner-lane knockout selection.
// ---------------------------------------------------------------------------
__global__ __launch_bounds__(256, 2) void knn_kernel(
    const short8* __restrict__ fragH, const short8* __restrict__ fragL,
    const float* __restrict__ sqp, int* __restrict__ nn9) {
  int wg = blockIdx.x;
  int r = wg & 7, j = wg >> 3;
  int b  = r + 8 * (j / 49);
  int qt = j % 49;
  int q0 = qt * 16;
  int t = threadIdx.x, lane = t & 63, w = t >> 6;

  __shared__ unsigned int dkS[16][DKW_];  // 53.5 KB keys
  __shared__ float qsqS[16];

  for (int i = t; i < 16 * 52; i += 256)
    dkS[i / 52][784 + i % 52] = 0xFFFFFFFFu;
  if (t < 16) qsqS[t] = sqp[(size_t)b * NP_ + q0 + t];
  __syncthreads();

  const float* sqb = sqp + (size_t)b * NP_;
  const short8* fH = fragH + (size_t)b * 6 * 64 * 64;
  const short8* fL = fragL + (size_t)b * 6 * 64 * 64;

  short8 aH[6], aL[6];
  #pragma unroll
  for (int ks = 0; ks < 6; ks++) {
    aH[ks] = fH[((size_t)ks * 64 + qt) * 64 + lane];
    aL[ks] = fL[((size_t)ks * 64 + qt) * 64 + lane];
  }

  int colL = lane & 15, rq = lane >> 4;
  const int wstart = (w == 0) ? 0 : (w == 1) ? 13 : (w == 2) ? 26 : 39;
  const int wend   = (w == 0) ? 13 : (w == 1) ? 26 : (w == 2) ? 39 : 49;

  int g = wstart;
  for (; g + 1 < wend; g += 2) {
    int g0 = g, g1 = g + 1;
    short8 B0h[6], B0l[6], B1h[6], B1l[6];
    #pragma unroll
    for (int ks = 0; ks < 6; ks++) {
      B0h[ks] = fH[((size_t)ks * 64 + g0) * 64 + lane];
      B0l[ks] = fL[((size_t)ks * 64 + g0) * 64 + lane];
      B1h[ks] = fH[((size_t)ks * 64 + g1) * 64 + lane];
      B1l[ks] = fL[((size_t)ks * 64 + g1) * 64 + lane];
    }
    float cs0 = sqb[g0 * 16 + colL];
    float cs1 = sqb[g1 * 16 + colL];
    f32x4 a00 = {0.f, 0.f, 0.f, 0.f}, a01 = a00, a02 = a00;
    f32x4 a10 = a00, a11 = a00, a12 = a00;
    #pragma unroll
    for (int ks = 0; ks < 6; ks++) {
      a00 = __builtin_amdgcn_mfma_f32_16x16x32_bf16(aH[ks], B0h[ks], a00, 0, 0, 0);
      a01 = __builtin_amdgcn_mfma_f32_16x16x32_bf16(aH[ks], B0l[ks], a01, 0, 0, 0);
      a02 = __builtin_amdgcn_mfma_f32_16x16x32_bf16(aL[ks], B0h[ks], a02, 0, 0, 0);
      a10 = __builtin_amdgcn_mfma_f32_16x16x32_bf16(aH[ks], B1h[ks], a10, 0, 0, 0);
      a11 = __builtin_amdgcn_mfma_f32_16x16x32_bf16(aH[ks], B1l[ks], a11, 0, 0, 0);
      a12 = __builtin_amdgcn_mfma_f32_16x16x32_bf16(aL[ks], B1h[ks], a12, 0, 0, 0);
    }
    #pragma unroll
    for (int rr = 0; rr < 4; rr++) {
      int row = rq * 4 + rr;
      float qs = qsqS[row];
      float g0v = __fadd_rn(__fadd_rn(a00[rr], a01[rr]), a02[rr]);
      float g1v = __fadd_rn(__fadd_rn(a10[rr], a11[rr]), a12[rr]);
      float d0 = __fadd_rn(__fsub_rn(qs, __fmul_rn(2.0f, g0v)), cs0);
      float d1 = __fadd_rn(__fsub_rn(qs, __fmul_rn(2.0f, g1v)), cs1);
      dkS[row][g0 * 16 + colL] = ford(d0);
      dkS[row][g1 * 16 + colL] = ford(d1);
    }
  }
  if (g < wend) {                       // odd tail: single group
    int g0 = g;
    short8 B0h[6], B0l[6];
    #pragma unroll
    for (int ks = 0; ks < 6; ks++) {
      B0h[ks] = fH[((size_t)ks * 64 + g0) * 64 + lane];
      B0l[ks] = fL[((size_t)ks * 64 + g0) * 64 + lane];
    }
    float cs0 = sqb[g0 * 16 + colL];
    f32x4 a00 = {0.f, 0.f, 0.f, 0.f}, a01 = a00, a02 = a00;
    #pragma unroll
    for (int ks = 0; ks < 6; ks++) {
      a00 = __builtin_amdgcn_mfma_f32_16x16x32_bf16(aH[ks], B0h[ks], a00, 0, 0, 0);
      a01 = __builtin_amdgcn_mfma_f32_16x16x32_bf16(aH[ks], B0l[ks], a01, 0, 0, 0);
      a02 = __builtin_amdgcn_mfma_f32_16x16x32_bf16(aL[ks], B0h[ks], a02, 0, 0, 0);
    }
    #pragma unroll
    for (int rr = 0; rr < 4; rr++) {
      int row = rq * 4 + rr;
      float qs = qsqS[row];
      float g0v = __fadd_rn(__fadd_rn(a00[rr], a01[rr]), a02[rr]);
      float d0 = __fadd_rn(__fsub_rn(qs, __fmul_rn(2.0f, g0v)), cs0);
      dkS[row][g0 * 16 + colL] = ford(d0);
    }
  }
  __syncthreads();

  for (int s = 0; s < 4; s++) {
    int row = w * 4 + s;
    unsigned int bv = 0xFFFFFFFFu; int bi = lane;
    #pragma unroll
    for (int it = 0; it < 13; it++) {
      unsigned int k = dkS[row][lane + 64 * it];
      if (k < bv) { bv = k; bi = lane + 64 * it; }
    }
    int* o = nn9 + ((size_t)b * N_ + q0 + row) * K_;
    for (int kk = 0; kk < K_; kk++) {
      unsigned long long mk = ((unsigned long long)bv << 10) | (unsigned int)bi;
      #pragma unroll
      for (int off = 1; off < 64; off <<= 1) {
        unsigned long long v2 = __shfl_xor(mk, off);
        mk = v2 < mk ? v2 : mk;
      }
      int widx = (int)(mk & 1023u);
      if (lane == 0) o[kk] = widx;
      if ((widx & 63) == lane) {
        dkS[row][widx] = 0xFFFFFFFFu;
        bv = 0xFFFFFFFFu; bi = lane;
        #pragma unroll
        for (int it = 0; it < 13; it++) {
          unsigned int k = dkS[row][lane + 64 * it];
          if (k < bv) { bv = k; bi = lane + 64 * it; }
        }
      }
    }
  }
}

// ---------------------------------------------------------------------------
// K3: FUSED gather + max-rel + grouped conv — merged halves, bf16 Wl (R24).
// ---------------------------------------------------------------------------
__global__ __launch_bounds__(256) void fconv_kernel(
    const float* __restrict__ xT, const int* __restrict__ nn9,
    const float* __restrict__ w, const float* __restrict__ bias,
    unsigned short* __restrict__ outpre, float* __restrict__ psum,
    float* __restrict__ pss) {
  int nt = blockIdx.x;
  int g  = blockIdx.y;
  int b  = blockIdx.z;
  int n0 = nt * 112;
  int t = threadIdx.x;

  __shared__ unsigned short Wl[96][98];   // 18.8 KB bf16
  __shared__ float Hl[96][112];           // 43.0 KB
  __shared__ unsigned short Il[112][K_];  // 2.0 KB

  const int* isrc = nn9 + ((size_t)b * N_ + n0) * K_;
  for (int i = t; i < 112 * K_; i += 256)
    Il[i / K_][i % K_] = (unsigned short)isrc[i];
  const float* wsrc = w + (size_t)(g * 96) * 96;
  for (int i = t; i < 96 * 96; i += 256)
    Wl[i / 96][i % 96] = f2bf(wsrc[i]);
  __syncthreads();

  if (t < 224) {
    int nl = t >> 1, half = t & 1;
    const float* xrow = xT + ((size_t)b * N_ + n0 + nl) * C_ + g * 48 + half * 24;
    float xv[24], mx[24];
    #pragma unroll
    for (int j = 0; j < 24; j += 4) {
      float4 v = *(const float4*)(xrow + j);
      xv[j] = v.x; xv[j + 1] = v.y; xv[j + 2] = v.z; xv[j + 3] = v.w;
      mx[j] = -1e30f; mx[j + 1] = -1e30f; mx[j + 2] = -1e30f; mx[j + 3] = -1e30f;
    }
    #pragma unroll
    for (int k = 0; k < K_; k++) {
      int idx = Il[nl][k];
      const float* nrow = xT + ((size_t)b * N_ + idx) * C_ + g * 48 + half * 24;
      #pragma unroll
      for (int j = 0; j < 24; j += 4) {
        float4 v = *(const float4*)(nrow + j);
        mx[j]     = fmaxf(mx[j], v.x);
        mx[j + 1] = fmaxf(mx[j + 1], v.y);
        mx[j + 2] = fmaxf(mx[j + 2], v.z);
        mx[j + 3] = fmaxf(mx[j + 3], v.w);
      }
    }
    #pragma unroll
    for (int j = 0; j < 24; j++) {
      int cl = half * 24 + j;
      Hl[2 * cl][nl]     = xv[j];
      Hl[2 * cl + 1][nl] = mx[j] - xv[j];
    }
  }
  __syncthreads();

  int tx = t & 15, ty = t >> 4;
  int tidx = b * 7 + nt;

  float o[6][7];
  #pragma unroll
  for (int i = 0; i < 6; i++)
    #pragma unroll
    for (int j = 0; j < 7; j++) o[i][j] = 0.f;

  for (int k = 0; k < 96; k++) {
    float wv[6];
    #pragma unroll
    for (int i = 0; i < 6; i++) wv[i] = bf2f(Wl[ty * 6 + i][k]);
    #pragma unroll
    for (int j = 0; j < 7; j++) {
      float hv = Hl[k][tx * 7 + j];
      #pragma unroll
      for (int i = 0; i < 6; i++) o[i][j] = __fmaf_rn(wv[i], hv, o[i][j]);
    }
  }

  #pragma unroll
  for (int i = 0; i < 6; i++) {
    int co = g * 96 + ty * 6 + i;
    float bv = bias[co];
    float s = 0.f, s2 = 0.f;
    unsigned short* orow =
        outpre + ((size_t)b * COUT_ + co) * N_ + n0 + tx * 7;
    #pragma unroll
    for (int j = 0; j < 7; j++) {
      float v = o[i][j] + bv;
      orow[j] = f2bf(v);
      s += v; s2 += v * v;
    }
    #pragma unroll
    for (int off = 1; off < 16; off <<= 1) {
      s  += __shfl_xor(s, off);
      s2 += __shfl_xor(s2, off);
    }
    if (tx == 0) {
      psum[co * NTILES_ + tidx] = s;
      pss [co * NTILES_ + tidx] = s2;
    }
  }
}

// ---------------------------------------------------------------------------
// K4: finalize BN stats -> per-channel affine a, b
// ---------------------------------------------------------------------------
__global__ __launch_bounds__(64) void stats_kernel(
    const float* __restrict__ psum, const float* __restrict__ pss,
    const float* __restrict__ gamma, const float* __restrict__ beta,
    float* __restrict__ af, float* __restrict__ bf) {
  int co = blockIdx.x;
  int l = threadIdx.x;
  double s = 0.0, s2 = 0.0;
  for (int i = l; i < NTILES_; i += 64) {
    s  += (double)psum[co * NTILES_ + i];
    s2 += (double)pss [co * NTILES_ + i];
  }
  #pragma unroll
  for (int o = 32; o > 0; o >>= 1) { s += __shfl_xor(s, o); s2 += __shfl_xor(s2, o); }
  if (l == 0) {
    const double cnt = (double)NPTS_;
    double mean = s / cnt;
    double var  = s2 / cnt - mean * mean;
    double rstd = 1.0 / sqrt(var + 1e-5);
    double a = (double)gamma[co] * rstd;
    af[co] = (float)a;
    bf[co] = (float)((double)beta[co] - mean * a);
  }
}

// ---------------------------------------------------------------------------
// K5: BN affine + exact GELU + fp32 store (8 elems/thread, bf16 input)
// ---------------------------------------------------------------------------
__global__ __launch_bounds__(256) void act_kernel(
    const unsigned short* __restrict__ outpre, const float* __restrict__ af,
    const float* __restrict__ bf, float* __restrict__ out) {
  size_t i = ((size_t)blockIdx.x * 256 + threadIdx.x) * 8;
  int co = (int)((i / N_) % COUT_);     // N_ % 8 == 0 -> co uniform
  float a = af[co], c = bf[co];
  union { uint4 u4; unsigned short us[8]; } pk;
  pk.u4 = *reinterpret_cast<const uint4*>(outpre + i);
  const float is2 = 0.70710678118654752f;
  float r[8];
  #pragma unroll
  for (int j = 0; j < 8; j++) {
    float y = __fmaf_rn(a, bf2f(pk.us[j]), c);
    r[j] = 0.5f * y * (1.0f + erff(y * is2));
  }
  float4 r0 = {r[0], r[1], r[2], r[3]};
  float4 r1 = {r[4], r[5], r[6], r[7]};
  *reinterpret_cast<float4*>(out + i) = r0;
  *reinterpret_cast<float4*>(out + i + 4) = r1;
}

// ---------------------------------------------------------------------------
extern "C" void kernel_launch(void* const* d_in, const int* in_sizes, int n_in,
                              void* d_out, int out_size, void* d_ws, size_t ws_size,
                              hipStream_t stream) {
  const float* x      = (const float*)d_in[0];
  const float* conv_w = (const float*)d_in[1];
  const float* conv_b = (const float*)d_in[2];
  const float* gamma  = (const float*)d_in[3];
  const float* beta   = (const float*)d_in[4];
  float* out = (float*)d_out;

  float* buf0 = (float*)d_ws;
  short8* fragH = (short8*)buf0;                         // [0, 3145728)
  short8* fragL = (short8*)(buf0 + 3145728);             // [3145728, 6291456)
  unsigned short* outpre = (unsigned short*)buf0;        // overlay (frags dead)
  float*  sqp   = buf0 + 9633792;                        // 32768
  int*    nn9   = (int*)(buf0 + 9666560);                // 225792
  float*  xT    = buf0 + 9892352;                        // 4816896
  float*  psum  = buf0 + 14709248;                       // 86016
  float*  pss   = psum + COUT_ * NTILES_;                // 86016
  float*  af    = pss + COUT_ * NTILES_;
  float*  bfv   = af + COUT_;

  hipLaunchKernelGGL(norm_kernel, dim3(NPTS_ / 64), dim3(256), 0, stream,
                     x, fragH, fragL, sqp, xT);
  hipLaunchKernelGGL(knn_kernel, dim3(49 * B_), dim3(256), 0, stream,
                     fragH, fragL, sqp, nn9);
  hipLaunchKernelGGL(fconv_kernel, dim3(7, 4, B_), dim3(256), 0, stream,
                     xT, nn9, conv_w, conv_b, outpre, psum, pss);
  hipLaunchKernelGGL(stats_kernel, dim3(COUT_), dim3(64), 0, stream,
                     psum, pss, gamma, beta, af, bfv);
  hipLaunchKernelGGL(act_kernel, dim3((B_ * COUT_ * N_) / (256 * 8)), dim3(256), 0, stream,
                     outpre, af, bfv, out);
}